// Round 1
// baseline (987.507 us; speedup 1.0000x reference)
//
#include <hip/hip_runtime.h>

#define HW   4096
#define Hh   64
#define Ww   64
#define NB   27
#define EPSBN 1e-5f

// ---------------------------------------------------------------------------
// Generic fused 1x1-conv (+optional BN+ReLU) GEMM:
//   out[b][o][p] = act( (sum_c w[o][c]*in[b][c][p] + bias[o]) folded BN )
// Tile: 32 outputs x 256 pixels per block; block = (64 px-lanes, 4 o-groups).
// Each thread: 8 outputs x 4 pixels = 32 accumulators. Weights staged in LDS
// in 64-channel chunks (broadcast reads, conflict-free).
// ---------------------------------------------------------------------------
__global__ __launch_bounds__(256)
void conv1x1_kernel(const float* __restrict__ in, const float* __restrict__ wgt,
                    const float* __restrict__ bias,
                    const float* __restrict__ gam, const float* __restrict__ bet,
                    const float* __restrict__ rmean, const float* __restrict__ rvar,
                    float* __restrict__ out, int Cin, int Ochan, int relu)
{
    __shared__ float wlds[32][64];
    const int tx = threadIdx.x;          // 0..63 pixel lanes
    const int ty = threadIdx.y;          // 0..3 output groups
    const int b  = blockIdx.z;
    const int obase = blockIdx.y * 32;
    const int pbase = blockIdx.x * 256;
    const float* inb = in + (size_t)b * Cin * HW;
    const int p0 = pbase + tx * 4;

    float acc[8][4];
    #pragma unroll
    for (int j = 0; j < 8; ++j) {
        #pragma unroll
        for (int k = 0; k < 4; ++k) acc[j][k] = 0.f;
    }

    const int tid  = ty * 64 + tx;
    const int wrow = tid >> 3;           // 0..31
    const int wcol = (tid & 7) * 8;      // 0..56

    for (int ck = 0; ck < Cin; ck += 64) {
        __syncthreads();
        const float* src = wgt + (size_t)(obase + wrow) * Cin + ck + wcol;
        *(float4*)&wlds[wrow][wcol]     = *(const float4*)src;
        *(float4*)&wlds[wrow][wcol + 4] = *(const float4*)(src + 4);
        __syncthreads();
        #pragma unroll 4
        for (int c4 = 0; c4 < 64; c4 += 4) {
            const float* xb = inb + (size_t)(ck + c4) * HW + p0;
            float4 x0 = *(const float4*)(xb);
            float4 x1 = *(const float4*)(xb + HW);
            float4 x2 = *(const float4*)(xb + 2 * HW);
            float4 x3 = *(const float4*)(xb + 3 * HW);
            #pragma unroll
            for (int j = 0; j < 8; ++j) {
                float4 wv = *(const float4*)&wlds[ty * 8 + j][c4];
                acc[j][0] = fmaf(wv.w, x3.x, fmaf(wv.z, x2.x, fmaf(wv.y, x1.x, fmaf(wv.x, x0.x, acc[j][0]))));
                acc[j][1] = fmaf(wv.w, x3.y, fmaf(wv.z, x2.y, fmaf(wv.y, x1.y, fmaf(wv.x, x0.y, acc[j][1]))));
                acc[j][2] = fmaf(wv.w, x3.z, fmaf(wv.z, x2.z, fmaf(wv.y, x1.z, fmaf(wv.x, x0.z, acc[j][2]))));
                acc[j][3] = fmaf(wv.w, x3.w, fmaf(wv.z, x2.w, fmaf(wv.y, x1.w, fmaf(wv.x, x0.w, acc[j][3]))));
            }
        }
    }

    #pragma unroll
    for (int j = 0; j < 8; ++j) {
        const int o = obase + ty * 8 + j;
        float s, off;
        if (gam != nullptr) {
            s   = gam[o] * rsqrtf(rvar[o] + EPSBN);
            off = fmaf(bias[o] - rmean[o], s, bet[o]);   // bias*s + be - m*s
        } else {
            s   = 1.f;
            off = bias[o];
        }
        float r0 = fmaf(acc[j][0], s, off);
        float r1 = fmaf(acc[j][1], s, off);
        float r2 = fmaf(acc[j][2], s, off);
        float r3 = fmaf(acc[j][3], s, off);
        if (relu) {
            r0 = fmaxf(r0, 0.f); r1 = fmaxf(r1, 0.f);
            r2 = fmaxf(r2, 0.f); r3 = fmaxf(r3, 0.f);
        }
        *(float4*)(out + ((size_t)b * Ochan + o) * HW + p0) = make_float4(r0, r1, r2, r3);
    }
}

// ---------------------------------------------------------------------------
// Attention: for each pixel, sim over 27 dilated neighbors (zero-padded:
// OOB => sim contribution exactly 0, still in softmax; value contribution 0),
// softmax over 27, context = weighted sum of value neighbors.
// Block = 64 pixels x 4 channel-groups (each group owns 64 of 256 channels);
// partial sims reduced through LDS so all 4 waves stay busy.
// ---------------------------------------------------------------------------
__global__ __launch_bounds__(256)
void attn_kernel(const float* __restrict__ key, const float* __restrict__ qry,
                 const float* __restrict__ val, float* __restrict__ ctx)
{
    __shared__ float psim[4][NB][64];
    const int tx = threadIdx.x;      // pixel lane 0..63
    const int ty = threadIdx.y;      // channel group 0..3
    const int b  = blockIdx.y;
    const int p  = blockIdx.x * 64 + tx;
    const int y  = p >> 6;
    const int xc = p & 63;
    const size_t bo = (size_t)b * 256 * HW;
    const float* kb = key + bo;
    const float* qb = qry + bo;
    const float* vb = val + bo;

    int offs[NB];
    unsigned vmask = 0;
    const int dil0 = 1, dil1 = 2, dil2 = 4;
    #pragma unroll
    for (int n = 0; n < NB; ++n) {
        const int d  = (n < 9) ? dil0 : (n < 18 ? dil1 : dil2);
        const int i  = (n / 3) % 3 - 1;
        const int j  = n % 3 - 1;
        const int dy = i * d, dx = j * d;
        offs[n] = dy * Ww + dx;
        const int yy = y + dy, xx = xc + dx;
        if (yy >= 0 && yy < Hh && xx >= 0 && xx < Ww) vmask |= (1u << n);
    }

    float sim[NB];
    #pragma unroll
    for (int n = 0; n < NB; ++n) sim[n] = 0.f;

    const int c0 = ty * 64;
    for (int c = c0; c < c0 + 64; ++c) {
        const float qv = qb[(size_t)c * HW + p];
        const float* kc = kb + (size_t)c * HW + p;
        #pragma unroll
        for (int n = 0; n < NB; ++n)
            if (vmask & (1u << n)) sim[n] = fmaf(kc[offs[n]], qv, sim[n]);
    }

    #pragma unroll
    for (int n = 0; n < NB; ++n) psim[ty][n][tx] = sim[n];
    __syncthreads();
    #pragma unroll
    for (int n = 0; n < NB; ++n)
        sim[n] = (psim[0][n][tx] + psim[1][n][tx]) + (psim[2][n][tx] + psim[3][n][tx]);

    float mx = sim[0];
    #pragma unroll
    for (int n = 1; n < NB; ++n) mx = fmaxf(mx, sim[n]);
    float sum = 0.f;
    #pragma unroll
    for (int n = 0; n < NB; ++n) { sim[n] = __expf(sim[n] - mx); sum += sim[n]; }
    const float inv = 1.f / sum;
    #pragma unroll
    for (int n = 0; n < NB; ++n) sim[n] *= inv;

    for (int c = c0; c < c0 + 64; ++c) {
        const float* vc = vb + (size_t)c * HW + p;
        float a = 0.f;
        #pragma unroll
        for (int n = 0; n < NB; ++n)
            if (vmask & (1u << n)) a = fmaf(sim[n], vc[offs[n]], a);
        ctx[bo + (size_t)c * HW + p] = a;
    }
}

extern "C" void kernel_launch(void* const* d_in, const int* in_sizes, int n_in,
                              void* d_out, int out_size, void* d_ws, size_t ws_size,
                              hipStream_t stream)
{
    (void)in_sizes; (void)n_in; (void)out_size; (void)ws_size;
    const float* x     = (const float*)d_in[0];
    const float* k1_w  = (const float*)d_in[1];
    const float* k1_b  = (const float*)d_in[2];
    const float* k1_g  = (const float*)d_in[3];
    const float* k1_be = (const float*)d_in[4];
    const float* k1_m  = (const float*)d_in[5];
    const float* k1_v  = (const float*)d_in[6];
    const float* k2_w  = (const float*)d_in[7];
    const float* k2_b  = (const float*)d_in[8];
    const float* k2_g  = (const float*)d_in[9];
    const float* k2_be = (const float*)d_in[10];
    const float* k2_m  = (const float*)d_in[11];
    const float* k2_v  = (const float*)d_in[12];
    const float* q1_w  = (const float*)d_in[13];
    const float* q1_b  = (const float*)d_in[14];
    const float* q1_g  = (const float*)d_in[15];
    const float* q1_be = (const float*)d_in[16];
    const float* q1_m  = (const float*)d_in[17];
    const float* q1_v  = (const float*)d_in[18];
    const float* q2_w  = (const float*)d_in[19];
    const float* q2_b  = (const float*)d_in[20];
    const float* q2_g  = (const float*)d_in[21];
    const float* q2_be = (const float*)d_in[22];
    const float* q2_m  = (const float*)d_in[23];
    const float* q2_v  = (const float*)d_in[24];
    const float* v_w   = (const float*)d_in[25];
    const float* v_b   = (const float*)d_in[26];
    const float* w_w   = (const float*)d_in[27];
    const float* w_b   = (const float*)d_in[28];

    float* ws = (float*)d_ws;
    const size_t S = (size_t)4 * 256 * HW;      // 4.19M floats per (B,256,HW) buffer
    float* v_buf   = ws;
    float* k1_buf  = ws + S;
    float* q1_buf  = ws + 2 * S;
    float* key_buf = ws + 3 * S;
    float* qry_buf = ws + 4 * S;
    float* ctx_buf = k1_buf;                    // k1 dead after stage 2 -> reuse

    const dim3 blk(64, 4);

    // stage 1: three GEMMs from x (Cin=512 -> 256)
    conv1x1_kernel<<<dim3(16, 8, 4), blk, 0, stream>>>(x, v_w, v_b,
        nullptr, nullptr, nullptr, nullptr, v_buf, 512, 256, 0);
    conv1x1_kernel<<<dim3(16, 8, 4), blk, 0, stream>>>(x, k1_w, k1_b,
        k1_g, k1_be, k1_m, k1_v, k1_buf, 512, 256, 1);
    conv1x1_kernel<<<dim3(16, 8, 4), blk, 0, stream>>>(x, q1_w, q1_b,
        q1_g, q1_be, q1_m, q1_v, q1_buf, 512, 256, 1);

    // stage 2: second projection convs (Cin=256 -> 256)
    conv1x1_kernel<<<dim3(16, 8, 4), blk, 0, stream>>>(k1_buf, k2_w, k2_b,
        k2_g, k2_be, k2_m, k2_v, key_buf, 256, 256, 1);
    conv1x1_kernel<<<dim3(16, 8, 4), blk, 0, stream>>>(q1_buf, q2_w, q2_b,
        q2_g, q2_be, q2_m, q2_v, qry_buf, 256, 256, 1);

    // stage 3: 27-neighbor attention
    attn_kernel<<<dim3(64, 4), blk, 0, stream>>>(key_buf, qry_buf, v_buf, ctx_buf);

    // stage 4: final conv (256 -> 512) straight into d_out
    conv1x1_kernel<<<dim3(16, 16, 4), blk, 0, stream>>>(ctx_buf, w_w, w_b,
        nullptr, nullptr, nullptr, nullptr, (float*)d_out, 256, 512, 0);
}

// Round 2
// 561.136 us; speedup vs baseline: 1.7598x; 1.7598x over previous
//
#include <hip/hip_runtime.h>

#define HW   4096
#define Hh   64
#define Ww   64
#define NB   27
#define EPSBN 1e-5f

// ---------------------------------------------------------------------------
// Generic fused 1x1-conv (+optional BN+ReLU) GEMM:
//   out[b][o][p] = act( (sum_c w[o][c]*in[b][c][p] + bias[o]) folded BN )
// Tile: 32 outputs x 256 pixels per block; block = (64 px-lanes, 4 o-groups).
// ---------------------------------------------------------------------------
__global__ __launch_bounds__(256)
void conv1x1_kernel(const float* __restrict__ in, const float* __restrict__ wgt,
                    const float* __restrict__ bias,
                    const float* __restrict__ gam, const float* __restrict__ bet,
                    const float* __restrict__ rmean, const float* __restrict__ rvar,
                    float* __restrict__ out, int Cin, int Ochan, int relu)
{
    __shared__ float wlds[32][64];
    const int tx = threadIdx.x;          // 0..63 pixel lanes
    const int ty = threadIdx.y;          // 0..3 output groups
    const int b  = blockIdx.z;
    const int obase = blockIdx.y * 32;
    const int pbase = blockIdx.x * 256;
    const float* inb = in + (size_t)b * Cin * HW;
    const int p0 = pbase + tx * 4;

    float acc[8][4];
    #pragma unroll
    for (int j = 0; j < 8; ++j) {
        #pragma unroll
        for (int k = 0; k < 4; ++k) acc[j][k] = 0.f;
    }

    const int tid  = ty * 64 + tx;
    const int wrow = tid >> 3;           // 0..31
    const int wcol = (tid & 7) * 8;      // 0..56

    for (int ck = 0; ck < Cin; ck += 64) {
        __syncthreads();
        const float* src = wgt + (size_t)(obase + wrow) * Cin + ck + wcol;
        *(float4*)&wlds[wrow][wcol]     = *(const float4*)src;
        *(float4*)&wlds[wrow][wcol + 4] = *(const float4*)(src + 4);
        __syncthreads();
        #pragma unroll 4
        for (int c4 = 0; c4 < 64; c4 += 4) {
            const float* xb = inb + (size_t)(ck + c4) * HW + p0;
            float4 x0 = *(const float4*)(xb);
            float4 x1 = *(const float4*)(xb + HW);
            float4 x2 = *(const float4*)(xb + 2 * HW);
            float4 x3 = *(const float4*)(xb + 3 * HW);
            #pragma unroll
            for (int j = 0; j < 8; ++j) {
                float4 wv = *(const float4*)&wlds[ty * 8 + j][c4];
                acc[j][0] = fmaf(wv.w, x3.x, fmaf(wv.z, x2.x, fmaf(wv.y, x1.x, fmaf(wv.x, x0.x, acc[j][0]))));
                acc[j][1] = fmaf(wv.w, x3.y, fmaf(wv.z, x2.y, fmaf(wv.y, x1.y, fmaf(wv.x, x0.y, acc[j][1]))));
                acc[j][2] = fmaf(wv.w, x3.z, fmaf(wv.z, x2.z, fmaf(wv.y, x1.z, fmaf(wv.x, x0.z, acc[j][2]))));
                acc[j][3] = fmaf(wv.w, x3.w, fmaf(wv.z, x2.w, fmaf(wv.y, x1.w, fmaf(wv.x, x0.w, acc[j][3]))));
            }
        }
    }

    #pragma unroll
    for (int j = 0; j < 8; ++j) {
        const int o = obase + ty * 8 + j;
        float s, off;
        if (gam != nullptr) {
            s   = gam[o] * rsqrtf(rvar[o] + EPSBN);
            off = fmaf(bias[o] - rmean[o], s, bet[o]);   // bias*s + be - m*s
        } else {
            s   = 1.f;
            off = bias[o];
        }
        float r0 = fmaf(acc[j][0], s, off);
        float r1 = fmaf(acc[j][1], s, off);
        float r2 = fmaf(acc[j][2], s, off);
        float r3 = fmaf(acc[j][3], s, off);
        if (relu) {
            r0 = fmaxf(r0, 0.f); r1 = fmaxf(r1, 0.f);
            r2 = fmaxf(r2, 0.f); r3 = fmaxf(r3, 0.f);
        }
        *(float4*)(out + ((size_t)b * Ochan + o) * HW + p0) = make_float4(r0, r1, r2, r3);
    }
}

// ---------------------------------------------------------------------------
// Attention, branch-free version. Neighbor coordinates are CLAMPED into the
// image so every load is unconditional (one big independent load clause per
// channel iteration -> MLP hides latency). Out-of-bounds neighbors are zeroed
// arithmetically: sim[n] *= valf[n] before softmax (matches zero-padded
// unfold: OOB dot-product contribution is exactly 0 but the slot still
// participates in softmax), and prob[n] *= valf[n] before the V pass (OOB
// value contribution is 0).
// Block = 64 pixels x 4 channel-groups; partial sims reduced through LDS.
// ---------------------------------------------------------------------------
__global__ __launch_bounds__(256)
void attn_kernel(const float* __restrict__ key, const float* __restrict__ qry,
                 const float* __restrict__ val, float* __restrict__ ctx)
{
    __shared__ float psim[4][NB][64];
    const int tx = threadIdx.x;      // pixel lane 0..63
    const int ty = threadIdx.y;      // channel group 0..3
    const int b  = blockIdx.y;
    const int p  = blockIdx.x * 64 + tx;
    const int y  = p >> 6;
    const int xc = p & 63;
    const size_t bo = (size_t)b * 256 * HW;
    const float* kb = key + bo;
    const float* qb = qry + bo;
    const float* vb = val + bo;

    int   idx[NB];     // clamped absolute pixel index of neighbor n
    float valf[NB];    // 1.0 if in-bounds else 0.0
    #pragma unroll
    for (int n = 0; n < NB; ++n) {
        const int d  = (n < 9) ? 1 : (n < 18 ? 2 : 4);
        const int i  = (n / 3) % 3 - 1;
        const int j  = n % 3 - 1;
        const int yy = y + i * d, xx = xc + j * d;
        const bool ok = ((unsigned)yy < (unsigned)Hh) && ((unsigned)xx < (unsigned)Ww);
        const int yyc = min(max(yy, 0), Hh - 1);
        const int xxc = min(max(xx, 0), Ww - 1);
        idx[n]  = yyc * Ww + xxc;
        valf[n] = ok ? 1.f : 0.f;
    }

    float sim[NB];
    #pragma unroll
    for (int n = 0; n < NB; ++n) sim[n] = 0.f;

    const int c0 = ty * 64;
    #pragma unroll 2
    for (int c = c0; c < c0 + 64; ++c) {
        const float  qv = qb[(size_t)c * HW + p];
        const float* kc = kb + (size_t)c * HW;
        #pragma unroll
        for (int n = 0; n < NB; ++n)
            sim[n] = fmaf(kc[idx[n]], qv, sim[n]);
    }

    #pragma unroll
    for (int n = 0; n < NB; ++n) psim[ty][n][tx] = sim[n] * valf[n];
    __syncthreads();
    #pragma unroll
    for (int n = 0; n < NB; ++n)
        sim[n] = (psim[0][n][tx] + psim[1][n][tx]) + (psim[2][n][tx] + psim[3][n][tx]);

    float mx = sim[0];
    #pragma unroll
    for (int n = 1; n < NB; ++n) mx = fmaxf(mx, sim[n]);
    float sum = 0.f;
    #pragma unroll
    for (int n = 0; n < NB; ++n) { sim[n] = __expf(sim[n] - mx); sum += sim[n]; }
    const float inv = 1.f / sum;
    #pragma unroll
    for (int n = 0; n < NB; ++n) sim[n] = sim[n] * inv * valf[n];  // prob, OOB zeroed

    #pragma unroll 2
    for (int c = c0; c < c0 + 64; ++c) {
        const float* vc = vb + (size_t)c * HW;
        float a = 0.f;
        #pragma unroll
        for (int n = 0; n < NB; ++n)
            a = fmaf(sim[n], vc[idx[n]], a);
        ctx[bo + (size_t)c * HW + p] = a;
    }
}

extern "C" void kernel_launch(void* const* d_in, const int* in_sizes, int n_in,
                              void* d_out, int out_size, void* d_ws, size_t ws_size,
                              hipStream_t stream)
{
    (void)in_sizes; (void)n_in; (void)out_size; (void)ws_size;
    const float* x     = (const float*)d_in[0];
    const float* k1_w  = (const float*)d_in[1];
    const float* k1_b  = (const float*)d_in[2];
    const float* k1_g  = (const float*)d_in[3];
    const float* k1_be = (const float*)d_in[4];
    const float* k1_m  = (const float*)d_in[5];
    const float* k1_v  = (const float*)d_in[6];
    const float* k2_w  = (const float*)d_in[7];
    const float* k2_b  = (const float*)d_in[8];
    const float* k2_g  = (const float*)d_in[9];
    const float* k2_be = (const float*)d_in[10];
    const float* k2_m  = (const float*)d_in[11];
    const float* k2_v  = (const float*)d_in[12];
    const float* q1_w  = (const float*)d_in[13];
    const float* q1_b  = (const float*)d_in[14];
    const float* q1_g  = (const float*)d_in[15];
    const float* q1_be = (const float*)d_in[16];
    const float* q1_m  = (const float*)d_in[17];
    const float* q1_v  = (const float*)d_in[18];
    const float* q2_w  = (const float*)d_in[19];
    const float* q2_b  = (const float*)d_in[20];
    const float* q2_g  = (const float*)d_in[21];
    const float* q2_be = (const float*)d_in[22];
    const float* q2_m  = (const float*)d_in[23];
    const float* q2_v  = (const float*)d_in[24];
    const float* v_w   = (const float*)d_in[25];
    const float* v_b   = (const float*)d_in[26];
    const float* w_w   = (const float*)d_in[27];
    const float* w_b   = (const float*)d_in[28];

    float* ws = (float*)d_ws;
    const size_t S = (size_t)4 * 256 * HW;      // floats per (B,256,HW) buffer
    float* v_buf   = ws;
    float* k1_buf  = ws + S;
    float* q1_buf  = ws + 2 * S;
    float* key_buf = ws + 3 * S;
    float* qry_buf = ws + 4 * S;
    float* ctx_buf = k1_buf;                    // k1 dead after stage 2 -> reuse

    const dim3 blk(64, 4);

    // stage 1: three GEMMs from x (Cin=512 -> 256)
    conv1x1_kernel<<<dim3(16, 8, 4), blk, 0, stream>>>(x, v_w, v_b,
        nullptr, nullptr, nullptr, nullptr, v_buf, 512, 256, 0);
    conv1x1_kernel<<<dim3(16, 8, 4), blk, 0, stream>>>(x, k1_w, k1_b,
        k1_g, k1_be, k1_m, k1_v, k1_buf, 512, 256, 1);
    conv1x1_kernel<<<dim3(16, 8, 4), blk, 0, stream>>>(x, q1_w, q1_b,
        q1_g, q1_be, q1_m, q1_v, q1_buf, 512, 256, 1);

    // stage 2: second projection convs (Cin=256 -> 256)
    conv1x1_kernel<<<dim3(16, 8, 4), blk, 0, stream>>>(k1_buf, k2_w, k2_b,
        k2_g, k2_be, k2_m, k2_v, key_buf, 256, 256, 1);
    conv1x1_kernel<<<dim3(16, 8, 4), blk, 0, stream>>>(q1_buf, q2_w, q2_b,
        q2_g, q2_be, q2_m, q2_v, qry_buf, 256, 256, 1);

    // stage 3: 27-neighbor attention
    attn_kernel<<<dim3(64, 4), blk, 0, stream>>>(key_buf, qry_buf, v_buf, ctx_buf);

    // stage 4: final conv (256 -> 512) straight into d_out
    conv1x1_kernel<<<dim3(16, 16, 4), blk, 0, stream>>>(ctx_buf, w_w, w_b,
        nullptr, nullptr, nullptr, nullptr, (float*)d_out, 256, 512, 0);
}